// Round 23
// baseline (27.852 us; speedup 1.0000x reference)
//
#include <hip/hip_runtime.h>
#include <stdint.h>

// Deformable 3x3 local correlation. CHANNEL-SPLIT occupancy doubling:
// each output (pixel,group) computed by 2 threads (8 channels each),
// combined via LDS. Block = 4 rows x 128 cols x 2 halves = 1024 thr;
// grid 512 -> 2 blocks/CU -> 32 waves/CU (problem previously capped at 16:
// one thread per output = 4096 waves = 50% of chip). w-tile 128 shrinks the
// staged window to 140 cells -> 71.7KB LDS, two blocks fit.
// f16 split-cell layout (r18): one aligned b128 = 8 channels of one column.
// r19/r21 lessons: don't duplicate setup across phases / don't cache >30
// regs across barriers. r6-r13: 64-VGPR cap; WRITE_SIZE >> 9.2MB = spill.
// left/right (2,128,64,256) f32, extra_offset (2,18,64,256) f32,
// out (2,72,64,256) f32. GROUPS=8, cg=16, S=9.

#define NB 2
#define CC 128
#define HH 64
#define WW 256
#define GG 8
#define CG 16
#define SS 9
#define HW (HH * WW)
#define TY 4                      // output rows per block
#define WT 128                    // output cols per block
#define RW 5                      // staged rows h0-RW .. h0+TY+RW-1 (14 interior)
#define NSLOT 16                  // 1 top guard + 14 data + 1 bottom guard
#define NCELL 140                 // 6 left guard + 128 + 6 right guard cols
#define CELL0 6                   // gcol = wbase + cell - CELL0
#define HALF 560                  // dwords per half-row = NCELL*4
#define SLOTQ (2 * HALF)          // 1120 dwords per row slot (mult of 32)
#define SMEMDW (NSLOT * SLOTQ)    // 17920 dw = 71.7 KB -> 2 blocks/CU

typedef __fp16 h2v __attribute__((ext_vector_type(2)));

static __device__ __forceinline__ uint32_t pkrtz(float a, float b) {
    h2v v = __builtin_amdgcn_cvt_pkrtz(a, b);
    return __builtin_bit_cast(uint32_t, v);
}
static __device__ __forceinline__ h2v u2h(uint32_t u) {
    return __builtin_bit_cast(h2v, u);
}

#if __has_builtin(__builtin_amdgcn_fdot2)
#define FDOT2(A, B, C) __builtin_amdgcn_fdot2((A), (B), (C), false)
#else
#define FDOT2(A, B, C) fmaf((float)(A).x, (float)(B).x, \
                            fmaf((float)(A).y, (float)(B).y, (C)))
#endif

// 8-channel dot at one (row,col): one aligned b128 (this thread's half)
#define DOT8(P, RES)                                                           \
  {                                                                            \
    const uint4 u_ = *(const uint4*)(P);                                       \
    RES = FDOT2(u2h(u_.x), u2h(lvpk[0]),                                       \
          FDOT2(u2h(u_.y), u2h(lvpk[1]),                                       \
          FDOT2(u2h(u_.z), u2h(lvpk[2]),                                       \
          FDOT2(u2h(u_.w), u2h(lvpk[3]), 0.0f))));                             \
  }

__global__ __launch_bounds__(1024) void corr_kernel(
    const float* __restrict__ left, const float* __restrict__ right,
    const float* __restrict__ eo, float* __restrict__ out)
{
    __shared__ uint32_t smem[SMEMDW];

    const int tid = threadIdx.x;
    const int lane = tid & 63;
    const int wv = tid >> 6;                 // wave 0..15
    const int bid = blockIdx.x;
    const int g = bid & 7;
    const int wh = (bid >> 3) & 1;           // w-half
    const int h0 = ((bid >> 4) & 15) << 2;
    const int n = bid >> 8;
    const int gch = g * CG;
    const int wbase = wh * WT;

    const int virt_row0 = h0 - RW;                        // slot 1 maps here
    const int row0 = max(0, virt_row0);
    const int row_last = min(HH - 1, h0 + TY + RW - 1);   // h0+8 interior
    const int nrows = row_last - row0 + 1;                // <= 14
    const int sbase = row0 - virt_row0 + 1;               // >= 1

    const int wcol7 = tid & 127;             // col within tile
    const int chh = (tid >> 7) & 1;          // channel half (wave-uniform)
    const int hh = tid >> 8;                 // 0..3 (wave-uniform)
    const int h = h0 + hh;
    const int wcol = wbase + wcol7;
    const int pix = h * WW + wcol;

    const float* rnb = right + (size_t)n * CC * HW;
    const float* lp  = left  + (size_t)(n * CC + gch + chh * 8) * HW + pix;
    const float* eob = eo + (size_t)n * SS * 2 * HW + pix;

    // ---- zero unstaged slots only (slot 0 & 15 always; edges more).
    // All 140 cells of staged slots are fully written (out-of-image cols
    // staged as 0.0), so no per-cell guards needed.
    {
        const bool staged = (wv >= sbase) && (wv < sbase + nrows);
        if (!staged) {
            uint32_t* slot = &smem[wv * SLOTQ];
            for (int i = lane; i < SLOTQ / 4; i += 64)
                *(uint4*)&slot[4 * i] = make_uint4(0u, 0u, 0u, 0u);
        }
    }

    // ---- hoist the 18 eo loads (latency overlaps staging below) ----
    float eox[SS], eoy[SS];
#pragma unroll
    for (int s = 0; s < SS; ++s) {
        eox[s] = eob[(2 * s) * HW];
        eoy[s] = eob[(2 * s + 1) * HW];
    }

    __syncthreads();                 // zeroing visible before staging writes

    // ---- stage window: wave wv -> row row0+wv; 3 passes over 140 cells ----
    if (wv < nrows) {
        const float* rowp = rnb + (size_t)gch * HW + (row0 + wv) * WW;
        uint32_t* slotp = &smem[(sbase + wv) * SLOTQ];
#pragma unroll
        for (int pass = 0; pass < 3; ++pass) {
            const int cell = pass * 64 + lane;
            if (cell < NCELL) {
                const int gcol = wbase + cell - CELL0;       // [-6, 261]
                const bool vc = (unsigned)gcol < (unsigned)WW;
                uint32_t pk8[8];
#pragma unroll
                for (int p = 0; p < 8; ++p) {
                    const float a = vc ? rowp[(size_t)(2 * p) * HW + gcol] : 0.0f;
                    const float b = vc ? rowp[(size_t)(2 * p + 1) * HW + gcol] : 0.0f;
                    pk8[p] = pkrtz(a, b);
                }
                *(uint4*)&slotp[4 * cell] =
                    make_uint4(pk8[0], pk8[1], pk8[2], pk8[3]);
                *(uint4*)&slotp[HALF + 4 * cell] =
                    make_uint4(pk8[4], pk8[5], pk8[6], pk8[7]);
            }
        }
    }

    // left values for this half, packed per pair (issued while staging drains)
    uint32_t lvpk[4];
#pragma unroll
    for (int p = 0; p < 4; ++p)
        lvpk[p] = pkrtz(lp[(size_t)(2 * p) * HW], lp[(size_t)(2 * p + 1) * HW]);

    float acc[SS];
#pragma unroll
    for (int s = 0; s < SS; ++s) acc[s] = 0.0f;

    __syncthreads();                 // window staged

    // ---- per-s: setup + 4 b128 gathers + dot (this thread's 8 channels) ----
#pragma unroll
    for (int s = 0; s < SS; ++s) {
        const float x = (float)(s / 3 - 1) + eox[s] + (float)wcol;
        const float y = (float)(s % 3 - 1) + eoy[s] + (float)h;
        const float x0f = floorf(x), y0f = floorf(y);
        const float fx0 = x - x0f, fx1 = 1.0f - fx0;
        const float fy0 = y - y0f, fy1 = 1.0f - fy0;
        const int x0 = (int)x0f, y0 = (int)y0f;
        const int x1 = x0 + 1,   y1 = y0 + 1;
        const bool vx0 = (unsigned)x0 < (unsigned)WW;
        const bool vx1 = (unsigned)x1 < (unsigned)WW;
        const bool vy0 = (unsigned)y0 < (unsigned)HH;
        const bool vy1 = (unsigned)y1 < (unsigned)HH;
        const float wA = (vx0 && vy0) ? fx1 * fy1 : 0.0f;   // (x0,y0)
        const float wB = (vx1 && vy0) ? fx0 * fy1 : 0.0f;   // (x1,y0)
        const float wC = (vx0 && vy1) ? fx1 * fy0 : 0.0f;   // (x0,y1)
        const float wD = (vx1 && vy1) ? fx0 * fy0 : 0.0f;   // (x1,y1)

        const bool bad =
            (vy0 && (y0 < row0 || y0 > row_last)) ||
            (vy1 && (y1 < row0 || y1 > row_last)) ||
            (vx0 && (x0 < wbase - CELL0)) ||
            (vx1 && (x1 > wbase + NCELL - CELL0 - 1));

        if (__builtin_expect(!bad, 1)) {
            const int xcell = min(max(x0 - wbase + CELL0, 0), NCELL - 2); // [0,138]
            const int rr = min(max(y0 - virt_row0 + 1, 0), NSLOT - 2);    // [0,14]
            const uint32_t* b0 = smem + rr * SLOTQ + chh * HALF + 4 * xcell;
            const uint32_t* b1 = b0 + SLOTQ;
            float dA, dB, dC, dD;
            DOT8(b0,     dA)          // (x0,y0)
            DOT8(b0 + 4, dB)          // (x1,y0)
            DOT8(b1,     dC)          // (x0,y1)
            DOT8(b1 + 4, dD)          // (x1,y1)
            acc[s] = fmaf(wA, dA, fmaf(wB, dB, fmaf(wC, dC, wD * dD)));
        } else {
            // ~never (|eo| > ~4 sigma): global fallback, own 8 channels
            const int cx0 = min(max(x0, 0), WW - 1), cx1 = min(max(x1, 0), WW - 1);
            const int cy0 = min(max(y0, 0), HH - 1), cy1 = min(max(y1, 0), HH - 1);
            float val = 0.0f;
#pragma unroll
            for (int p = 0; p < 4; ++p) {
                const h2v lv = u2h(lvpk[p]);
#pragma unroll
                for (int c2 = 0; c2 < 2; ++c2) {
                    const float* rp2 =
                        rnb + (size_t)(gch + chh * 8 + 2 * p + c2) * HW;
                    const float v = wA * rp2[cy0 * WW + cx0] + wB * rp2[cy0 * WW + cx1]
                                  + wC * rp2[cy1 * WW + cx0] + wD * rp2[cy1 * WW + cx1];
                    val += (c2 ? (float)lv.y : (float)lv.x) * v;
                }
            }
            acc[s] = val;
        }
    }

    // ---- combine halves through LDS (reuse staged-plane memory) ----
    __syncthreads();                 // all compute done; smem reusable
    if (chh == 1) {
        float* cs = (float*)smem + (hh * WT + wcol7) * SS;   // 4608 floats
#pragma unroll
        for (int s = 0; s < SS; ++s) cs[s] = acc[s];
    }
    __syncthreads();
    if (chh == 0) {
        const float* cs = (const float*)smem + (hh * WT + wcol7) * SS;
        float* ob = out + ((size_t)(n * GG + g) * SS) * HW + pix;
#pragma unroll
        for (int s = 0; s < SS; ++s)
            ob[s * HW] = (acc[s] + cs[s]) * (1.0f / CG);
    }
}

extern "C" void kernel_launch(void* const* d_in, const int* in_sizes, int n_in,
                              void* d_out, int out_size, void* d_ws, size_t ws_size,
                              hipStream_t stream) {
    const float* left  = (const float*)d_in[0];
    const float* right = (const float*)d_in[1];
    const float* eo    = (const float*)d_in[2];
    float* out = (float*)d_out;
    (void)d_ws; (void)ws_size; (void)in_sizes; (void)n_in; (void)out_size;

    dim3 grid(NB * (HH / TY) * (WW / WT) * GG);   // 512 blocks
    dim3 block(TY * WT * 2);                       // 1024 thr: (hh, chhalf, w)
    corr_kernel<<<grid, block, 0, stream>>>(left, right, eo, out);
}

// Round 28
// 21.075 us; speedup vs baseline: 1.3216x; 1.3216x over previous
//
#include <hip/hip_runtime.h>
#include <stdint.h>

// Deformable 3x3 local correlation — converged structure (r22) + NaN fix.
// r24 ROOT CAUSE: tap read rp0+4 reaches cell xc+2 <= 258 (first PAD cell);
// guard-only zeroing covered only cells 0 & 257, so pads held stale LDS
// bits. Weights are 0 there, but 0*Inf = NaN -> nondeterministic failure
// (r22 passed on lucky leftovers). Fix: staged slots zero cells 0 and
// 257..263 (guard + full pad) of each half — 64 dwords = 1/lane.
// Structure: f16 channel-major SPLIT-CELL LDS; one aligned ds_read_b128 =
// 8 channels of one column -> 8 b128 + 32 fdot2 per tap-site; all 16
// channels LDS-resident (135KB, 1 block/CU), 2 barriers; 18 eo loads
// hoisted pre-barrier. Rejected by measurement: quad-pack (r16), SW
// pipeline (r17), T14 split staging (r19), full hoist (r21), occupancy
// splits (r11/r23). 64-VGPR cap not overridable (r7-r9); WRITE_SIZE >>
// 9.2MB = spill tripwire.
// left/right (2,128,64,256) f32, extra_offset (2,18,64,256) f32,
// out (2,72,64,256) f32. GROUPS=8, cg=16, S=9.

#define NB 2
#define CC 128
#define HH 64
#define WW 256
#define GG 8
#define CG 16
#define SS 9
#define HW (HH * WW)
#define TY 4                      // output rows per block
#define RW 5                      // staged rows h0-RW .. h0+TY+RW-1 (14 interior)
#define NSLOT 16                  // 1 top guard + 14 data + 1 bottom guard
#define HALFDW 1056               // dwords per half-row (264 cells x 4dw incl pad)
#define SLOTQ (2 * HALFDW)        // 2112 dwords per row slot
#define SMEMDW (NSLOT * SLOTQ)    // 33792 dw = 135.2 KB -> 1 block/CU

typedef __fp16 h2v __attribute__((ext_vector_type(2)));

static __device__ __forceinline__ uint32_t pkrtz(float a, float b) {
    h2v v = __builtin_amdgcn_cvt_pkrtz(a, b);
    return __builtin_bit_cast(uint32_t, v);
}
static __device__ __forceinline__ h2v u2h(uint32_t u) {
    return __builtin_bit_cast(h2v, u);
}

#if __has_builtin(__builtin_amdgcn_fdot2)
#define FDOT2(A, B, C) __builtin_amdgcn_fdot2((A), (B), (C), false)
#else
#define FDOT2(A, B, C) fmaf((float)(A).x, (float)(B).x, \
                            fmaf((float)(A).y, (float)(B).y, (C)))
#endif

// 16-channel dot at one (row,col): lo b128 (pairs 0-3) + hi b128 (pairs 4-7)
#define DOT16(LOP, RES)                                                        \
  {                                                                            \
    const uint4 u0_ = *(const uint4*)(LOP);                                    \
    const uint4 u1_ = *(const uint4*)((LOP) + HALFDW);                         \
    RES = FDOT2(u2h(u0_.x), u2h(lvpk[0]),                                      \
          FDOT2(u2h(u0_.y), u2h(lvpk[1]),                                      \
          FDOT2(u2h(u0_.z), u2h(lvpk[2]),                                      \
          FDOT2(u2h(u0_.w), u2h(lvpk[3]),                                      \
          FDOT2(u2h(u1_.x), u2h(lvpk[4]),                                      \
          FDOT2(u2h(u1_.y), u2h(lvpk[5]),                                      \
          FDOT2(u2h(u1_.z), u2h(lvpk[6]),                                      \
          FDOT2(u2h(u1_.w), u2h(lvpk[7]), 0.0f))))))));                        \
  }

__global__ __launch_bounds__(1024) void corr_kernel(
    const float* __restrict__ left, const float* __restrict__ right,
    const float* __restrict__ eo, float* __restrict__ out)
{
    __shared__ uint32_t smem[SMEMDW];

    const int tid = threadIdx.x;
    const int lane = tid & 63;
    const int wv = tid >> 6;                 // wave 0..15
    const int bid = blockIdx.x;
    const int g = bid & (GG - 1);
    const int h0 = ((bid >> 3) & 15) << 2;
    const int n = bid >> 7;
    const int gch = g * CG;

    const int virt_row0 = h0 - RW;                        // slot 1 maps here
    const int row0 = max(0, virt_row0);
    const int row_last = min(HH - 1, h0 + TY + RW - 1);   // h0+8 interior
    const int nrows = row_last - row0 + 1;                // <= 14
    const int sbase = row0 - virt_row0 + 1;

    const int hh = tid >> 8;                 // 0..3 (wave-uniform)
    const int h = h0 + hh;
    const int wcol = tid & 255;
    const int pix = h * WW + wcol;

    const float* rnb = right + (size_t)n * CC * HW;
    const float* lp  = left  + (size_t)(n * CC + gch) * HW + pix;
    const float* eob = eo + (size_t)n * SS * 2 * HW + pix;

    // ---- zeroing: wave wv owns slot wv ----
    // unstaged slots: fully zeroed. staged slots: cells 0 and 257..263
    // (right guard + ENTIRE pad) of each half — reads reach cell xc+2 <= 258
    // (r24 NaN root cause), and pads must never hold stale Inf/NaN bits.
    // 2 halves x 8 cells x 4 dw = 64 dwords: one per lane.
    {
        const bool staged = (wv >= sbase) && (wv < sbase + nrows);
        uint32_t* slot = &smem[wv * SLOTQ];
        if (!staged) {
            for (int i = lane; i < SLOTQ / 4; i += 64)
                *(uint4*)&slot[4 * i] = make_uint4(0u, 0u, 0u, 0u);
        } else {
            const int half = lane >> 5;              // 0: lo, 1: hi
            const int j = lane & 31;
            const int csel = j >> 2;                 // 0..7
            const int cell = (csel == 0) ? 0 : (256 + csel);   // 0, 257..263
            const int dwi = j & 3;
            slot[half * HALFDW + cell * 4 + dwi] = 0u;
        }
    }

    // ---- hoist the 18 eo loads (latency overlaps staging below) ----
    float eox[SS], eoy[SS];
#pragma unroll
    for (int s = 0; s < SS; ++s) {
        eox[s] = eob[(2 * s) * HW];
        eoy[s] = eob[(2 * s + 1) * HW];
    }

    __syncthreads();                 // zeroing visible before staging writes

    // ---- stage all 16 channels, 4 column passes ----
#pragma unroll
    for (int pass = 0; pass < 4; ++pass) {
        if (wv < nrows) {
            const int cq = 64 * pass + lane;             // col 0..255
            const float* s0 = rnb + (size_t)gch * HW + (row0 + wv) * WW + cq;
            uint32_t pk8[8];
#pragma unroll
            for (int p = 0; p < 8; ++p)
                pk8[p] = pkrtz(s0[(size_t)(2 * p) * HW],
                               s0[(size_t)(2 * p + 1) * HW]);
            uint32_t* dst = &smem[(sbase + wv) * SLOTQ + 4 * (cq + 1)];
            *(uint4*)dst            = make_uint4(pk8[0], pk8[1], pk8[2], pk8[3]);
            *(uint4*)(dst + HALFDW) = make_uint4(pk8[4], pk8[5], pk8[6], pk8[7]);
        }
    }

    // left values, packed per pair (computed while staging drains)
    uint32_t lvpk[8];
#pragma unroll
    for (int p = 0; p < 8; ++p)
        lvpk[p] = pkrtz(lp[(size_t)(2 * p) * HW], lp[(size_t)(2 * p + 1) * HW]);

    float acc[SS];
#pragma unroll
    for (int s = 0; s < SS; ++s) acc[s] = 0.0f;

    __syncthreads();                 // all channels staged

    // ---- per-s: setup (from hoisted eo) + gather + dot ----
#pragma unroll
    for (int s = 0; s < SS; ++s) {
        const float x = (float)(s / 3 - 1) + eox[s] + (float)wcol;
        const float y = (float)(s % 3 - 1) + eoy[s] + (float)h;
        const float x0f = floorf(x), y0f = floorf(y);
        const float fx0 = x - x0f, fx1 = 1.0f - fx0;
        const float fy0 = y - y0f, fy1 = 1.0f - fy0;
        const int x0 = (int)x0f, y0 = (int)y0f;
        const int x1 = x0 + 1,   y1 = y0 + 1;
        const bool vx0 = (unsigned)x0 < (unsigned)WW;
        const bool vx1 = (unsigned)x1 < (unsigned)WW;
        const bool vy0 = (unsigned)y0 < (unsigned)HH;
        const bool vy1 = (unsigned)y1 < (unsigned)HH;
        const float wA = (vx0 && vy0) ? fx1 * fy1 : 0.0f;   // (x0,y0)
        const float wB = (vx1 && vy0) ? fx0 * fy1 : 0.0f;   // (x1,y0)
        const float wC = (vx0 && vy1) ? fx1 * fy0 : 0.0f;   // (x0,y1)
        const float wD = (vx1 && vy1) ? fx0 * fy0 : 0.0f;   // (x1,y1)

        const bool bad = (vy0 && (y0 < row0 || y0 > row_last)) ||
                         (vy1 && (y1 < row0 || y1 > row_last));

        if (__builtin_expect(!bad, 1)) {
            const int xc = min(max(x0, -1), WW);                       // [-1,256]
            const int rr = min(max(y0 - virt_row0 + 1, 0), NSLOT - 2); // [0,14]
            const uint32_t* rp0 = smem + rr * SLOTQ + 4 * (xc + 1);
            const uint32_t* rp1 = rp0 + SLOTQ;
            float dA, dB, dC, dD;
            DOT16(rp0,     dA)        // (x0,y0)
            DOT16(rp0 + 4, dB)        // (x1,y0)
            DOT16(rp1,     dC)        // (x0,y1)
            DOT16(rp1 + 4, dD)        // (x1,y1)
            acc[s] += fmaf(wA, dA, fmaf(wB, dB, fmaf(wC, dC, wD * dD)));
        } else {
            // ~never (needs |eo| > ~4 sigma): full-precision global fallback
            const int cx0 = min(max(x0, 0), WW - 1), cx1 = min(max(x1, 0), WW - 1);
            const int cy0 = min(max(y0, 0), HH - 1), cy1 = min(max(y1, 0), HH - 1);
#pragma unroll
            for (int p = 0; p < 8; ++p) {
                const h2v lv = u2h(lvpk[p]);
#pragma unroll
                for (int c2 = 0; c2 < 2; ++c2) {
                    const float* rp2 = rnb + (size_t)(gch + 2 * p + c2) * HW;
                    const float v = wA * rp2[cy0 * WW + cx0] + wB * rp2[cy0 * WW + cx1]
                                  + wC * rp2[cy1 * WW + cx0] + wD * rp2[cy1 * WW + cx1];
                    acc[s] += (c2 ? (float)lv.y : (float)lv.x) * v;
                }
            }
        }
    }

    float* ob = out + ((size_t)(n * GG + g) * SS) * HW + pix;
#pragma unroll
    for (int s = 0; s < SS; ++s)
        ob[s * HW] = acc[s] * (1.0f / CG);
}

extern "C" void kernel_launch(void* const* d_in, const int* in_sizes, int n_in,
                              void* d_out, int out_size, void* d_ws, size_t ws_size,
                              hipStream_t stream) {
    const float* left  = (const float*)d_in[0];
    const float* right = (const float*)d_in[1];
    const float* eo    = (const float*)d_in[2];
    float* out = (float*)d_out;
    (void)d_ws; (void)ws_size; (void)in_sizes; (void)n_in; (void)out_size;

    dim3 grid(NB * (HH / TY) * GG);   // 256 blocks: (n, h-tile, group)
    dim3 block(1024);                  // 16 waves; thread = (hh, w)
    corr_kernel<<<grid, block, 0, stream>>>(left, right, eo, out);
}